// Round 1
// baseline (216.770 us; speedup 1.0000x reference)
//
#include <hip/hip_runtime.h>
#include <hip/hip_bf16.h>

typedef unsigned short u16;
typedef unsigned int u32;
typedef __bf16 bf16x8 __attribute__((ext_vector_type(8)));
typedef float f32x4 __attribute__((ext_vector_type(4)));

#define AS1 __attribute__((address_space(1)))
#define AS3 __attribute__((address_space(3)))

#define NB 2
#define NS 2048
#define ND 1024
#define NH 16
#define NK 64

__device__ __forceinline__ u16 f2bf(float f) {
  u32 u = __builtin_bit_cast(u32, f);
  return (u16)((u + 0x7FFFu + ((u >> 16) & 1u)) >> 16);  // RNE
}

// ---------------------------------------------------------------------------
// Stage a 64x64 bf16 tile (global row stride rs elems) into LDS.
// LDS is linear [64][64]; logical 16B-slot s of row r lives at physical slot
// s ^ (r&7). global_load_lds writes linearly (wave base + lane*16B), so the
// swizzle is applied by permuting the per-lane GLOBAL source address
// (both-sides-or-neither rule; the read side applies the same XOR).
// ---------------------------------------------------------------------------
__device__ __forceinline__ void stage_tile(u16* lds, const u16* __restrict__ src, int rs,
                                           int wid, int lane) {
#pragma unroll
  for (int i = 0; i < 2; ++i) {
    int c = wid * 128 + i * 64 + lane;  // 16B chunk id, 0..511
    int row = c >> 3;
    int kc = (c & 7) ^ (row & 7);       // pre-swizzled source slot
    __builtin_amdgcn_global_load_lds((const AS1 u32*)(src + row * rs + kc * 8),
                                     (AS3 u32*)(lds + (wid * 128 + i * 64) * 8), 16, 0, 0);
  }
}

// Read the 8-elem (16B) MFMA operand fragment at logical (row, k = ks*32 + (lane>>4)*8).
__device__ __forceinline__ bf16x8 read_frag(const u16* lds, int row, int ks, int lane) {
  int slot = ((lane >> 4) + ks * 4) ^ (row & 7);
  return *(const bf16x8*)(lds + row * 64 + slot * 8);
}

// ---------------------------------------------------------------------------
// f32 -> bf16 convert (emb)
// ---------------------------------------------------------------------------
__global__ __launch_bounds__(256) void convert_kernel(const float* __restrict__ src,
                                                      u16* __restrict__ dst, int n) {
  int i = (blockIdx.x * 256 + threadIdx.x) * 4;
  if (i >= n) return;
  float4 v = *(const float4*)(src + i);
  u32 w0 = (u32)f2bf(v.x) | ((u32)f2bf(v.y) << 16);
  u32 w1 = (u32)f2bf(v.z) | ((u32)f2bf(v.w) << 16);
  uint2 w; w.x = w0; w.y = w1;
  *(uint2*)(dst + i) = w;
}

// ---------------------------------------------------------------------------
// Transposing f32->bf16 convert: src [R][C] f32 (per z), dst [C][R] bf16.
// block (32,8), 32x32 tiles via LDS.
// ---------------------------------------------------------------------------
__global__ __launch_bounds__(256) void transpose_conv(const float* __restrict__ src,
                                                      u16* __restrict__ dst, int R, int C) {
  __shared__ float tile[32][33];
  size_t base = (size_t)blockIdx.z * R * C;
  src += base;
  dst += base;
  int c0 = blockIdx.x * 32, r0 = blockIdx.y * 32;
  int tx = threadIdx.x, ty = threadIdx.y;
#pragma unroll
  for (int i = 0; i < 4; ++i)
    tile[ty + 8 * i][tx] = src[(size_t)(r0 + ty + 8 * i) * C + c0 + tx];
  __syncthreads();
#pragma unroll
  for (int i = 0; i < 4; ++i)
    dst[(size_t)(c0 + ty + 8 * i) * R + r0 + tx] = f2bf(tile[tx][ty + 8 * i]);
}

// ---------------------------------------------------------------------------
// QKV projection: per (row-tile mt, head h, which in {q,k,v}):
//   out[s, n] = emb[s, :] @ W[h][:, n] + b[h][n]
// A tile: emb rows (64 x 64), B tile: Wt[h] rows n (K-contiguous after the
// host-side transpose). Q written pre-scaled by 1/8; V written transposed
// [bh, dk, s] so attention's PV B-operand is K-contiguous.
// ---------------------------------------------------------------------------
__global__ __launch_bounds__(256) void qkv_kernel(
    const u16* __restrict__ emb, const u16* __restrict__ Wqt, const u16* __restrict__ Wkt,
    const u16* __restrict__ Wvt, const float* __restrict__ bq, const float* __restrict__ bk,
    const float* __restrict__ bv, u16* __restrict__ Q, u16* __restrict__ K,
    u16* __restrict__ Vt) {
  __shared__ alignas(16) u16 lds_a[64 * 64];
  __shared__ alignas(16) u16 lds_b[64 * 64];
  int tid = threadIdx.x, lane = tid & 63, wid = tid >> 6;
  int mt = blockIdx.x, h = blockIdx.y, which = blockIdx.z;
  const u16* Wt = (which == 0 ? Wqt : which == 1 ? Wkt : Wvt) + h * (ND * NK);
  const float* bias = (which == 0 ? bq : which == 1 ? bk : bv) + h * NK;
  int m0 = mt * 64;
  int col = lane & 15;
  f32x4 zero4 = {0.f, 0.f, 0.f, 0.f};
  f32x4 acc[4] = {zero4, zero4, zero4, zero4};
  for (int k0 = 0; k0 < ND; k0 += 64) {
    stage_tile(lds_a, emb + m0 * ND + k0, ND, wid, lane);
    stage_tile(lds_b, Wt + k0, ND, wid, lane);
    __syncthreads();
#pragma unroll
    for (int ks = 0; ks < 2; ++ks) {
      bf16x8 a = read_frag(lds_a, wid * 16 + col, ks, lane);
#pragma unroll
      for (int f = 0; f < 4; ++f) {
        bf16x8 b = read_frag(lds_b, f * 16 + col, ks, lane);
        acc[f] = __builtin_amdgcn_mfma_f32_16x16x32_bf16(a, b, acc[f], 0, 0, 0);
      }
    }
    __syncthreads();
  }
  int rbase = m0 + wid * 16 + (lane >> 4) * 4;
#pragma unroll
  for (int f = 0; f < 4; ++f) {
    int n = f * 16 + col;
    float bn = bias[n];
#pragma unroll
    for (int r = 0; r < 4; ++r) {
      int m = rbase + r;
      int b = m >> 11, s = m & (NS - 1);
      float v = acc[f][r] + bn;
      if (which == 0) {
        Q[((b * NH + h) * NS + s) * NK + n] = f2bf(v * 0.125f);  // fold 1/sqrt(dk)
      } else if (which == 1) {
        K[((b * NH + h) * NS + s) * NK + n] = f2bf(v);
      } else {
        Vt[((b * NH + h) * NK + n) * NS + s] = f2bf(v);
      }
    }
  }
}

// ---------------------------------------------------------------------------
// Causal flash attention. Block = (q-tile of 64 rows) x (b,h). 4 waves x 16
// q-rows. K-tiles of 64; causal => tiles t = 0..qt, only t==qt needs a mask.
// Online softmax fully wave-parallel (16-lane shfl_xor reductions).
// ---------------------------------------------------------------------------
__global__ __launch_bounds__(256) void attn_kernel(const u16* __restrict__ Q,
                                                   const u16* __restrict__ K,
                                                   const u16* __restrict__ Vt,
                                                   u16* __restrict__ ctx) {
  __shared__ alignas(16) u16 lds_k[64 * 64];
  __shared__ alignas(16) u16 lds_v[64 * 64];
  __shared__ alignas(16) u16 p_lds[4][16 * 72];  // per-wave, stride 72 = conflict-free b128
  int tid = threadIdx.x, lane = tid & 63, wid = tid >> 6;
  int qt = blockIdx.x, bh = blockIdx.y;
  const u16* Qb = Q + bh * (NS * NK);
  const u16* Kb = K + bh * (NS * NK);
  const u16* Vb = Vt + bh * (NK * NS);
  int q0 = qt * 64;
  int col = lane & 15;
  // Q fragments (A layout: row = lane&15), held for the whole block
  int qrow_a = q0 + wid * 16 + col;
  bf16x8 qf0 = *(const bf16x8*)(Qb + qrow_a * NK + (lane >> 4) * 8);
  bf16x8 qf1 = *(const bf16x8*)(Qb + qrow_a * NK + 32 + (lane >> 4) * 8);
  f32x4 zero4 = {0.f, 0.f, 0.f, 0.f};
  f32x4 acc[4] = {zero4, zero4, zero4, zero4};
  float m[4], l[4];
#pragma unroll
  for (int r = 0; r < 4; ++r) { m[r] = -1e30f; l[r] = 0.f; }
  int qrow_c = q0 + wid * 16 + (lane >> 4) * 4;  // C-layout row base
  u16* pw = p_lds[wid];

  for (int t = 0; t <= qt; ++t) {
    stage_tile(lds_k, Kb + t * 64 * NK, NK, wid, lane);
    stage_tile(lds_v, Vb + t * 64, NS, wid, lane);
    __syncthreads();
    // S = Q K^T (pre-scaled), C layout: col -> k-col, row -> q
    f32x4 sc[4];
#pragma unroll
    for (int f = 0; f < 4; ++f) {
      bf16x8 b0 = read_frag(lds_k, f * 16 + col, 0, lane);
      sc[f] = __builtin_amdgcn_mfma_f32_16x16x32_bf16(qf0, b0, zero4, 0, 0, 0);
      bf16x8 b1 = read_frag(lds_k, f * 16 + col, 1, lane);
      sc[f] = __builtin_amdgcn_mfma_f32_16x16x32_bf16(qf1, b1, sc[f], 0, 0, 0);
    }
    if (t == qt) {  // diagonal tile: causal mask k > q
#pragma unroll
      for (int f = 0; f < 4; ++f) {
        int kg = t * 64 + f * 16 + col;
#pragma unroll
        for (int r = 0; r < 4; ++r)
          if (kg > qrow_c + r) sc[f][r] = -1e30f;
      }
    }
    // wave-parallel online softmax (row = reduce over 16 lanes sharing lane>>4)
    float mx[4];
#pragma unroll
    for (int r = 0; r < 4; ++r)
      mx[r] = fmaxf(fmaxf(sc[0][r], sc[1][r]), fmaxf(sc[2][r], sc[3][r]));
#pragma unroll
    for (int off = 1; off < 16; off <<= 1)
#pragma unroll
      for (int r = 0; r < 4; ++r) mx[r] = fmaxf(mx[r], __shfl_xor(mx[r], off));
    float alpha[4];
#pragma unroll
    for (int r = 0; r < 4; ++r) {
      float mn = fmaxf(m[r], mx[r]);
      alpha[r] = exp2f((m[r] - mn) * 1.44269504f);
      m[r] = mn;
    }
    float rs[4] = {0.f, 0.f, 0.f, 0.f};
#pragma unroll
    for (int f = 0; f < 4; ++f)
#pragma unroll
      for (int r = 0; r < 4; ++r) {
        float p = exp2f((sc[f][r] - m[r]) * 1.44269504f);
        sc[f][r] = p;
        rs[r] += p;
      }
#pragma unroll
    for (int off = 1; off < 16; off <<= 1)
#pragma unroll
      for (int r = 0; r < 4; ++r) rs[r] += __shfl_xor(rs[r], off);
#pragma unroll
    for (int r = 0; r < 4; ++r) l[r] = l[r] * alpha[r] + rs[r];
#pragma unroll
    for (int f = 0; f < 4; ++f)
#pragma unroll
      for (int r = 0; r < 4; ++r) acc[f][r] *= alpha[r];
    // P (C layout) -> per-wave LDS -> A-layout fragments
#pragma unroll
    for (int f = 0; f < 4; ++f)
#pragma unroll
      for (int r = 0; r < 4; ++r)
        pw[((lane >> 4) * 4 + r) * 72 + f * 16 + col] = f2bf(sc[f][r]);
    __syncthreads();
#pragma unroll
    for (int ks = 0; ks < 2; ++ks) {
      bf16x8 pa = *(const bf16x8*)(pw + col * 72 + ks * 32 + (lane >> 4) * 8);
#pragma unroll
      for (int f = 0; f < 4; ++f) {
        bf16x8 vb = read_frag(lds_v, f * 16 + col, ks, lane);
        acc[f] = __builtin_amdgcn_mfma_f32_16x16x32_bf16(pa, vb, acc[f], 0, 0, 0);
      }
    }
    __syncthreads();  // protect lds_k/lds_v before next stage
  }
  // normalize + write ctx as [b][s][h*64+dk] (head-major concat)
  int b = bh >> 4, h = bh & 15;
#pragma unroll
  for (int r = 0; r < 4; ++r) {
    float inv = 1.0f / l[r];
    int s = qrow_c + r;
#pragma unroll
    for (int f = 0; f < 4; ++f)
      ctx[(b * NS + s) * ND + h * NK + f * 16 + col] = f2bf(acc[f][r] * inv);
  }
}

// ---------------------------------------------------------------------------
// Output projection: out[m, n] = ctx[m, :] @ Wo[:, n] + bo[n], f32 out.
// ---------------------------------------------------------------------------
__global__ __launch_bounds__(256) void outproj_kernel(const u16* __restrict__ ctx,
                                                      const u16* __restrict__ Wot,
                                                      const float* __restrict__ bo,
                                                      float* __restrict__ out) {
  __shared__ alignas(16) u16 lds_a[64 * 64];
  __shared__ alignas(16) u16 lds_b[64 * 64];
  int tid = threadIdx.x, lane = tid & 63, wid = tid >> 6;
  int m0 = blockIdx.x * 64, n0 = blockIdx.y * 64;
  int col = lane & 15;
  f32x4 zero4 = {0.f, 0.f, 0.f, 0.f};
  f32x4 acc[4] = {zero4, zero4, zero4, zero4};
  for (int k0 = 0; k0 < ND; k0 += 64) {
    stage_tile(lds_a, ctx + m0 * ND + k0, ND, wid, lane);
    stage_tile(lds_b, Wot + n0 * ND + k0, ND, wid, lane);
    __syncthreads();
#pragma unroll
    for (int ks = 0; ks < 2; ++ks) {
      bf16x8 a = read_frag(lds_a, wid * 16 + col, ks, lane);
#pragma unroll
      for (int f = 0; f < 4; ++f) {
        bf16x8 b = read_frag(lds_b, f * 16 + col, ks, lane);
        acc[f] = __builtin_amdgcn_mfma_f32_16x16x32_bf16(a, b, acc[f], 0, 0, 0);
      }
    }
    __syncthreads();
  }
  int rbase = m0 + wid * 16 + (lane >> 4) * 4;
#pragma unroll
  for (int f = 0; f < 4; ++f) {
    int n = n0 + f * 16 + col;
    float bn = bo[n];
#pragma unroll
    for (int r = 0; r < 4; ++r) out[(rbase + r) * ND + n] = acc[f][r] + bn;
  }
}

// ---------------------------------------------------------------------------
extern "C" void kernel_launch(void* const* d_in, const int* in_sizes, int n_in,
                              void* d_out, int out_size, void* d_ws, size_t ws_size,
                              hipStream_t stream) {
  (void)in_sizes; (void)n_in; (void)out_size;
  const float* emb = (const float*)d_in[0];
  const float* Wq = (const float*)d_in[1];
  const float* bq = (const float*)d_in[2];
  const float* Wk = (const float*)d_in[3];
  const float* bk = (const float*)d_in[4];
  const float* Wv = (const float*)d_in[5];
  const float* bv = (const float*)d_in[6];
  const float* Wo = (const float*)d_in[7];
  const float* bo = (const float*)d_in[8];
  float* out = (float*)d_out;

  const size_t EMB_N = (size_t)NB * NS * ND;      // 4194304
  const size_t W_N = (size_t)NH * ND * NK;        // 1048576
  const size_t QKV_N = (size_t)NB * NH * NS * NK; // 4194304
  // ws layout (u16 elems). ctx aliases emb_bf (emb consumed before ctx written).
  if (ws_size < (EMB_N + 4 * W_N + 3 * QKV_N) * sizeof(u16)) return;
  u16* ws = (u16*)d_ws;
  u16* emb_bf = ws;
  u16* Wqt = emb_bf + EMB_N;
  u16* Wkt = Wqt + W_N;
  u16* Wvt = Wkt + W_N;
  u16* Wot = Wvt + W_N;
  u16* Qb = Wot + W_N;
  u16* Kb = Qb + QKV_N;
  u16* Vtb = Kb + QKV_N;
  u16* ctxb = emb_bf;  // alias

  convert_kernel<<<dim3((int)(EMB_N / 4 / 256)), dim3(256), 0, stream>>>(emb, emb_bf,
                                                                         (int)EMB_N);
  dim3 tb(32, 8);
  transpose_conv<<<dim3(2, 32, 16), tb, 0, stream>>>(Wq, Wqt, ND, NK);
  transpose_conv<<<dim3(2, 32, 16), tb, 0, stream>>>(Wk, Wkt, ND, NK);
  transpose_conv<<<dim3(2, 32, 16), tb, 0, stream>>>(Wv, Wvt, ND, NK);
  transpose_conv<<<dim3(32, 32, 1), tb, 0, stream>>>(Wo, Wot, ND, ND);
  qkv_kernel<<<dim3(64, 16, 3), dim3(256), 0, stream>>>(emb_bf, Wqt, Wkt, Wvt, bq, bk, bv,
                                                        Qb, Kb, Vtb);
  attn_kernel<<<dim3(32, 32), dim3(256), 0, stream>>>(Qb, Kb, Vtb, ctxb);
  outproj_kernel<<<dim3(64, 16), dim3(256), 0, stream>>>(ctxb, Wot, bo, out);
}

// Round 2
// 146.337 us; speedup vs baseline: 1.4813x; 1.4813x over previous
//
#include <hip/hip_runtime.h>
#include <hip/hip_bf16.h>

typedef unsigned short u16;
typedef unsigned int u32;
typedef __bf16 bf16x8 __attribute__((ext_vector_type(8)));
typedef float f32x4 __attribute__((ext_vector_type(4)));

#define AS1 __attribute__((address_space(1)))
#define AS3 __attribute__((address_space(3)))

#define NB 2
#define NS 2048
#define ND 1024
#define NH 16
#define NK 64

__device__ __forceinline__ u16 f2bf(float f) {
  u32 u = __builtin_bit_cast(u32, f);
  return (u16)((u + 0x7FFFu + ((u >> 16) & 1u)) >> 16);  // RNE
}

// ---------------------------------------------------------------------------
// Stage a 64x64 bf16 tile (global row stride rs elems) into LDS.
// LDS is linear [64][64]; logical 16B-slot s of row r lives at physical slot
// s ^ (r&7). global_load_lds writes linearly (wave base + lane*16B), so the
// swizzle is applied by permuting the per-lane GLOBAL source address
// (both-sides-or-neither rule; the read side applies the same XOR).
// ---------------------------------------------------------------------------
__device__ __forceinline__ void stage_tile(u16* lds, const u16* __restrict__ src, int rs,
                                           int wid, int lane) {
#pragma unroll
  for (int i = 0; i < 2; ++i) {
    int c = wid * 128 + i * 64 + lane;  // 16B chunk id, 0..511
    int row = c >> 3;
    int kc = (c & 7) ^ (row & 7);       // pre-swizzled source slot
    __builtin_amdgcn_global_load_lds((const AS1 u32*)(src + row * rs + kc * 8),
                                     (AS3 u32*)(lds + (wid * 128 + i * 64) * 8), 16, 0, 0);
  }
}

// Read the 8-elem (16B) MFMA operand fragment at logical (row, k = ks*32 + (lane>>4)*8).
__device__ __forceinline__ bf16x8 read_frag(const u16* lds, int row, int ks, int lane) {
  int slot = ((lane >> 4) + ks * 4) ^ (row & 7);
  return *(const bf16x8*)(lds + row * 64 + slot * 8);
}

// ---------------------------------------------------------------------------
// f32 -> bf16 convert (emb)
// ---------------------------------------------------------------------------
__global__ __launch_bounds__(256) void convert_kernel(const float* __restrict__ src,
                                                      u16* __restrict__ dst, int n) {
  int i = (blockIdx.x * 256 + threadIdx.x) * 4;
  if (i >= n) return;
  float4 v = *(const float4*)(src + i);
  u32 w0 = (u32)f2bf(v.x) | ((u32)f2bf(v.y) << 16);
  u32 w1 = (u32)f2bf(v.z) | ((u32)f2bf(v.w) << 16);
  uint2 w; w.x = w0; w.y = w1;
  *(uint2*)(dst + i) = w;
}

// ---------------------------------------------------------------------------
// Transposing f32->bf16 convert: src [R][C] f32 (per z), dst [C][R] bf16.
// block (32,8), 32x32 tiles via LDS.
// ---------------------------------------------------------------------------
__global__ __launch_bounds__(256) void transpose_conv(const float* __restrict__ src,
                                                      u16* __restrict__ dst, int R, int C) {
  __shared__ float tile[32][33];
  size_t base = (size_t)blockIdx.z * R * C;
  src += base;
  dst += base;
  int c0 = blockIdx.x * 32, r0 = blockIdx.y * 32;
  int tx = threadIdx.x, ty = threadIdx.y;
#pragma unroll
  for (int i = 0; i < 4; ++i)
    tile[ty + 8 * i][tx] = src[(size_t)(r0 + ty + 8 * i) * C + c0 + tx];
  __syncthreads();
#pragma unroll
  for (int i = 0; i < 4; ++i)
    dst[(size_t)(c0 + ty + 8 * i) * R + r0 + tx] = f2bf(tile[tx][ty + 8 * i]);
}

// ---------------------------------------------------------------------------
// QKV projection: per (row-tile mt, head h, which in {q,k,v}):
//   out[s, n] = emb[s, :] @ W[h][:, n] + b[h][n]
// ---------------------------------------------------------------------------
__global__ __launch_bounds__(256) void qkv_kernel(
    const u16* __restrict__ emb, const u16* __restrict__ Wqt, const u16* __restrict__ Wkt,
    const u16* __restrict__ Wvt, const float* __restrict__ bq, const float* __restrict__ bk,
    const float* __restrict__ bv, u16* __restrict__ Q, u16* __restrict__ K,
    u16* __restrict__ Vt) {
  __shared__ alignas(16) u16 lds_a[64 * 64];
  __shared__ alignas(16) u16 lds_b[64 * 64];
  int tid = threadIdx.x, lane = tid & 63, wid = tid >> 6;
  int mt = blockIdx.x, h = blockIdx.y, which = blockIdx.z;
  const u16* Wt = (which == 0 ? Wqt : which == 1 ? Wkt : Wvt) + h * (ND * NK);
  const float* bias = (which == 0 ? bq : which == 1 ? bk : bv) + h * NK;
  int m0 = mt * 64;
  int col = lane & 15;
  f32x4 zero4 = {0.f, 0.f, 0.f, 0.f};
  f32x4 acc[4] = {zero4, zero4, zero4, zero4};
  for (int k0 = 0; k0 < ND; k0 += 64) {
    stage_tile(lds_a, emb + m0 * ND + k0, ND, wid, lane);
    stage_tile(lds_b, Wt + k0, ND, wid, lane);
    __syncthreads();
#pragma unroll
    for (int ks = 0; ks < 2; ++ks) {
      bf16x8 a = read_frag(lds_a, wid * 16 + col, ks, lane);
#pragma unroll
      for (int f = 0; f < 4; ++f) {
        bf16x8 b = read_frag(lds_b, f * 16 + col, ks, lane);
        acc[f] = __builtin_amdgcn_mfma_f32_16x16x32_bf16(a, b, acc[f], 0, 0, 0);
      }
    }
    __syncthreads();
  }
  int rbase = m0 + wid * 16 + (lane >> 4) * 4;
#pragma unroll
  for (int f = 0; f < 4; ++f) {
    int n = f * 16 + col;
    float bn = bias[n];
#pragma unroll
    for (int r = 0; r < 4; ++r) {
      int m = rbase + r;
      int b = m >> 11, s = m & (NS - 1);
      float v = acc[f][r] + bn;
      if (which == 0) {
        Q[((b * NH + h) * NS + s) * NK + n] = f2bf(v * 0.125f);  // fold 1/sqrt(dk)
      } else if (which == 1) {
        K[((b * NH + h) * NS + s) * NK + n] = f2bf(v);
      } else {
        Vt[((b * NH + h) * NK + n) * NS + s] = f2bf(v);
      }
    }
  }
}

// ---------------------------------------------------------------------------
// Causal flash attention. Block = (q-tile of 64 rows) x (b,h). 4 waves x 16
// q-rows. K-tiles of 64; causal => tiles t = 0..qt, only t==qt needs a mask.
//
// R2 restructure (latency-bound fix):
//  - K/V double-buffered in LDS; prefetch of tile t+1 issued at the TOP of
//    step t, so the compiler's vmcnt(0)-before-barrier at the END of the step
//    drains loads that had the whole compute phase to land (latency hidden).
//  - ONE barrier per step (p_lds is per-wave: only in-wave lgkmcnt ordering
//    needed, which the compiler inserts).
//  - LPT dispatch: qt = 31 - blockIdx.y with bh on x, so the 32-step blocks
//    are dispatched first and the queue tail holds 1-step blocks.
// ---------------------------------------------------------------------------
__global__ __launch_bounds__(256) void attn_kernel(const u16* __restrict__ Q,
                                                   const u16* __restrict__ K,
                                                   const u16* __restrict__ Vt,
                                                   u16* __restrict__ ctx) {
  __shared__ alignas(16) u16 lds_k[2][64 * 64];
  __shared__ alignas(16) u16 lds_v[2][64 * 64];
  __shared__ alignas(16) u16 p_lds[4][16 * 72];  // per-wave, stride 72 = conflict-free b128
  int tid = threadIdx.x, lane = tid & 63, wid = tid >> 6;
  int bh = blockIdx.x;
  int qt = (int)gridDim.y - 1 - (int)blockIdx.y;  // longest blocks dispatch first
  const u16* Qb = Q + bh * (NS * NK);
  const u16* Kb = K + bh * (NS * NK);
  const u16* Vb = Vt + bh * (NK * NS);
  int q0 = qt * 64;
  int col = lane & 15;
  // Q fragments (A layout: row = lane&15), held for the whole block
  int qrow_a = q0 + wid * 16 + col;
  bf16x8 qf0 = *(const bf16x8*)(Qb + qrow_a * NK + (lane >> 4) * 8);
  bf16x8 qf1 = *(const bf16x8*)(Qb + qrow_a * NK + 32 + (lane >> 4) * 8);
  f32x4 zero4 = {0.f, 0.f, 0.f, 0.f};
  f32x4 acc[4] = {zero4, zero4, zero4, zero4};
  float m[4], l[4];
#pragma unroll
  for (int r = 0; r < 4; ++r) { m[r] = -1e30f; l[r] = 0.f; }
  int qrow_c = q0 + wid * 16 + (lane >> 4) * 4;  // C-layout row base
  u16* pw = p_lds[wid];
  int nt = qt + 1;

  // prologue: stage tile 0 into buffer 0
  stage_tile(lds_k[0], Kb, NK, wid, lane);
  stage_tile(lds_v[0], Vb, NS, wid, lane);
  __syncthreads();

  for (int t = 0; t < nt; ++t) {
    int cur = t & 1;
    if (t + 1 < nt) {  // prefetch next tile into the other buffer
      stage_tile(lds_k[cur ^ 1], Kb + (t + 1) * 64 * NK, NK, wid, lane);
      stage_tile(lds_v[cur ^ 1], Vb + (t + 1) * 64, NS, wid, lane);
    }
    const u16* lk = lds_k[cur];
    const u16* lv = lds_v[cur];
    // S = Q K^T (pre-scaled), C layout: col -> k-col, row -> q
    f32x4 sc[4];
#pragma unroll
    for (int f = 0; f < 4; ++f) {
      bf16x8 b0 = read_frag(lk, f * 16 + col, 0, lane);
      sc[f] = __builtin_amdgcn_mfma_f32_16x16x32_bf16(qf0, b0, zero4, 0, 0, 0);
      bf16x8 b1 = read_frag(lk, f * 16 + col, 1, lane);
      sc[f] = __builtin_amdgcn_mfma_f32_16x16x32_bf16(qf1, b1, sc[f], 0, 0, 0);
    }
    if (t == qt) {  // diagonal tile: causal mask k > q
#pragma unroll
      for (int f = 0; f < 4; ++f) {
        int kg = t * 64 + f * 16 + col;
#pragma unroll
        for (int r = 0; r < 4; ++r)
          if (kg > qrow_c + r) sc[f][r] = -1e30f;
      }
    }
    // wave-parallel online softmax (row = reduce over 16 lanes sharing lane>>4)
    float mx[4];
#pragma unroll
    for (int r = 0; r < 4; ++r)
      mx[r] = fmaxf(fmaxf(sc[0][r], sc[1][r]), fmaxf(sc[2][r], sc[3][r]));
#pragma unroll
    for (int off = 1; off < 16; off <<= 1)
#pragma unroll
      for (int r = 0; r < 4; ++r) mx[r] = fmaxf(mx[r], __shfl_xor(mx[r], off));
    float alpha[4];
#pragma unroll
    for (int r = 0; r < 4; ++r) {
      float mn = fmaxf(m[r], mx[r]);
      alpha[r] = exp2f((m[r] - mn) * 1.44269504f);
      m[r] = mn;
    }
    float rs[4] = {0.f, 0.f, 0.f, 0.f};
#pragma unroll
    for (int f = 0; f < 4; ++f)
#pragma unroll
      for (int r = 0; r < 4; ++r) {
        float p = exp2f((sc[f][r] - m[r]) * 1.44269504f);
        sc[f][r] = p;
        rs[r] += p;
      }
#pragma unroll
    for (int off = 1; off < 16; off <<= 1)
#pragma unroll
      for (int r = 0; r < 4; ++r) rs[r] += __shfl_xor(rs[r], off);
#pragma unroll
    for (int r = 0; r < 4; ++r) l[r] = l[r] * alpha[r] + rs[r];
#pragma unroll
    for (int f = 0; f < 4; ++f)
#pragma unroll
      for (int r = 0; r < 4; ++r) acc[f][r] *= alpha[r];
    // P (C layout) -> per-wave LDS slab -> A-layout fragments (no barrier:
    // slab is private to this wave; compiler inserts lgkmcnt ordering)
#pragma unroll
    for (int f = 0; f < 4; ++f)
#pragma unroll
      for (int r = 0; r < 4; ++r)
        pw[((lane >> 4) * 4 + r) * 72 + f * 16 + col] = f2bf(sc[f][r]);
#pragma unroll
    for (int ks = 0; ks < 2; ++ks) {
      bf16x8 pa = *(const bf16x8*)(pw + col * 72 + ks * 32 + (lane >> 4) * 8);
#pragma unroll
      for (int f = 0; f < 4; ++f) {
        bf16x8 vb = read_frag(lv, f * 16 + col, ks, lane);
        acc[f] = __builtin_amdgcn_mfma_f32_16x16x32_bf16(pa, vb, acc[f], 0, 0, 0);
      }
    }
    // single barrier: all waves done reading buf[cur] (lgkmcnt(0) drained by
    // compiler) AND this step's prefetch drained (vmcnt(0)) after a full
    // compute phase of latency hiding.
    __syncthreads();
  }
  // normalize + write ctx as [b][s][h*64+dk] (head-major concat)
  int b = bh >> 4, h = bh & 15;
#pragma unroll
  for (int r = 0; r < 4; ++r) {
    float inv = 1.0f / l[r];
    int s = qrow_c + r;
#pragma unroll
    for (int f = 0; f < 4; ++f)
      ctx[(b * NS + s) * ND + h * NK + f * 16 + col] = f2bf(acc[f][r] * inv);
  }
}

// ---------------------------------------------------------------------------
// Output projection: out[m, n] = ctx[m, :] @ Wo[:, n] + bo[n], f32 out.
// ---------------------------------------------------------------------------
__global__ __launch_bounds__(256) void outproj_kernel(const u16* __restrict__ ctx,
                                                      const u16* __restrict__ Wot,
                                                      const float* __restrict__ bo,
                                                      float* __restrict__ out) {
  __shared__ alignas(16) u16 lds_a[64 * 64];
  __shared__ alignas(16) u16 lds_b[64 * 64];
  int tid = threadIdx.x, lane = tid & 63, wid = tid >> 6;
  int m0 = blockIdx.x * 64, n0 = blockIdx.y * 64;
  int col = lane & 15;
  f32x4 zero4 = {0.f, 0.f, 0.f, 0.f};
  f32x4 acc[4] = {zero4, zero4, zero4, zero4};
  for (int k0 = 0; k0 < ND; k0 += 64) {
    stage_tile(lds_a, ctx + m0 * ND + k0, ND, wid, lane);
    stage_tile(lds_b, Wot + n0 * ND + k0, ND, wid, lane);
    __syncthreads();
#pragma unroll
    for (int ks = 0; ks < 2; ++ks) {
      bf16x8 a = read_frag(lds_a, wid * 16 + col, ks, lane);
#pragma unroll
      for (int f = 0; f < 4; ++f) {
        bf16x8 b = read_frag(lds_b, f * 16 + col, ks, lane);
        acc[f] = __builtin_amdgcn_mfma_f32_16x16x32_bf16(a, b, acc[f], 0, 0, 0);
      }
    }
    __syncthreads();
  }
  int rbase = m0 + wid * 16 + (lane >> 4) * 4;
#pragma unroll
  for (int f = 0; f < 4; ++f) {
    int n = n0 + f * 16 + col;
    float bn = bo[n];
#pragma unroll
    for (int r = 0; r < 4; ++r) out[(rbase + r) * ND + n] = acc[f][r] + bn;
  }
}

// ---------------------------------------------------------------------------
extern "C" void kernel_launch(void* const* d_in, const int* in_sizes, int n_in,
                              void* d_out, int out_size, void* d_ws, size_t ws_size,
                              hipStream_t stream) {
  (void)in_sizes; (void)n_in; (void)out_size;
  const float* emb = (const float*)d_in[0];
  const float* Wq = (const float*)d_in[1];
  const float* bq = (const float*)d_in[2];
  const float* Wk = (const float*)d_in[3];
  const float* bk = (const float*)d_in[4];
  const float* Wv = (const float*)d_in[5];
  const float* bv = (const float*)d_in[6];
  const float* Wo = (const float*)d_in[7];
  const float* bo = (const float*)d_in[8];
  float* out = (float*)d_out;

  const size_t EMB_N = (size_t)NB * NS * ND;      // 4194304
  const size_t W_N = (size_t)NH * ND * NK;        // 1048576
  const size_t QKV_N = (size_t)NB * NH * NS * NK; // 4194304
  // ws layout (u16 elems). ctx aliases emb_bf (emb consumed before ctx written).
  if (ws_size < (EMB_N + 4 * W_N + 3 * QKV_N) * sizeof(u16)) return;
  u16* ws = (u16*)d_ws;
  u16* emb_bf = ws;
  u16* Wqt = emb_bf + EMB_N;
  u16* Wkt = Wqt + W_N;
  u16* Wvt = Wkt + W_N;
  u16* Wot = Wvt + W_N;
  u16* Qb = Wot + W_N;
  u16* Kb = Qb + QKV_N;
  u16* Vtb = Kb + QKV_N;
  u16* ctxb = emb_bf;  // alias

  convert_kernel<<<dim3((int)(EMB_N / 4 / 256)), dim3(256), 0, stream>>>(emb, emb_bf,
                                                                         (int)EMB_N);
  dim3 tb(32, 8);
  transpose_conv<<<dim3(2, 32, 16), tb, 0, stream>>>(Wq, Wqt, ND, NK);
  transpose_conv<<<dim3(2, 32, 16), tb, 0, stream>>>(Wk, Wkt, ND, NK);
  transpose_conv<<<dim3(2, 32, 16), tb, 0, stream>>>(Wv, Wvt, ND, NK);
  transpose_conv<<<dim3(32, 32, 1), tb, 0, stream>>>(Wo, Wot, ND, ND);
  qkv_kernel<<<dim3(64, 16, 3), dim3(256), 0, stream>>>(emb_bf, Wqt, Wkt, Wvt, bq, bk, bv,
                                                        Qb, Kb, Vtb);
  attn_kernel<<<dim3(32, 32), dim3(256), 0, stream>>>(Qb, Kb, Vtb, ctxb);
  outproj_kernel<<<dim3(64, 16), dim3(256), 0, stream>>>(ctxb, Wot, bo, out);
}

// Round 3
// 139.628 us; speedup vs baseline: 1.5525x; 1.0480x over previous
//
#include <hip/hip_runtime.h>
#include <hip/hip_bf16.h>

typedef unsigned short u16;
typedef unsigned int u32;
typedef __bf16 bf16x8 __attribute__((ext_vector_type(8)));
typedef float f32x4 __attribute__((ext_vector_type(4)));

#define AS1 __attribute__((address_space(1)))
#define AS3 __attribute__((address_space(3)))

#define NB 2
#define NS 2048
#define ND 1024
#define NH 16
#define NK 64

__device__ __forceinline__ u16 f2bf(float f) {
  u32 u = __builtin_bit_cast(u32, f);
  return (u16)((u + 0x7FFFu + ((u >> 16) & 1u)) >> 16);  // RNE
}

// packed f32x2 -> bf16x2 (RNE) in one VALU op; no builtin on gfx950 (m240)
__device__ __forceinline__ u32 cvt_pk_bf16(float lo, float hi) {
  u32 u;
  asm("v_cvt_pk_bf16_f32 %0, %1, %2" : "=v"(u) : "v"(lo), "v"(hi));
  return u;
}

// ---------------------------------------------------------------------------
// Stage a 64x64 bf16 tile (global row stride rs elems) into LDS.
// LDS is linear [64][64]; logical 16B-slot s of row r lives at physical slot
// s ^ (r&7). global_load_lds writes linearly (wave base + lane*16B), so the
// swizzle is applied by permuting the per-lane GLOBAL source address
// (both-sides-or-neither rule; the read side applies the same XOR).
// ---------------------------------------------------------------------------
__device__ __forceinline__ void stage_tile(u16* lds, const u16* __restrict__ src, int rs,
                                           int wid, int lane) {
#pragma unroll
  for (int i = 0; i < 2; ++i) {
    int c = wid * 128 + i * 64 + lane;  // 16B chunk id, 0..511
    int row = c >> 3;
    int kc = (c & 7) ^ (row & 7);       // pre-swizzled source slot
    __builtin_amdgcn_global_load_lds((const AS1 u32*)(src + row * rs + kc * 8),
                                     (AS3 u32*)(lds + (wid * 128 + i * 64) * 8), 16, 0, 0);
  }
}

// Read the 8-elem (16B) MFMA operand fragment at logical (row, k = ks*32 + (lane>>4)*8).
__device__ __forceinline__ bf16x8 read_frag(const u16* lds, int row, int ks, int lane) {
  int slot = ((lane >> 4) + ks * 4) ^ (row & 7);
  return *(const bf16x8*)(lds + row * 64 + slot * 8);
}

// ---------------------------------------------------------------------------
// f32 -> bf16 convert (emb)
// ---------------------------------------------------------------------------
__global__ __launch_bounds__(256) void convert_kernel(const float* __restrict__ src,
                                                      u16* __restrict__ dst, int n) {
  int i = (blockIdx.x * 256 + threadIdx.x) * 4;
  if (i >= n) return;
  float4 v = *(const float4*)(src + i);
  u32 w0 = cvt_pk_bf16(v.x, v.y);
  u32 w1 = cvt_pk_bf16(v.z, v.w);
  uint2 w; w.x = w0; w.y = w1;
  *(uint2*)(dst + i) = w;
}

// ---------------------------------------------------------------------------
// Transposing f32->bf16 convert: src [R][C] f32 (per z), dst [C][R] bf16.
// block (32,8), 32x32 tiles via LDS.
// ---------------------------------------------------------------------------
__global__ __launch_bounds__(256) void transpose_conv(const float* __restrict__ src,
                                                      u16* __restrict__ dst, int R, int C) {
  __shared__ float tile[32][33];
  size_t base = (size_t)blockIdx.z * R * C;
  src += base;
  dst += base;
  int c0 = blockIdx.x * 32, r0 = blockIdx.y * 32;
  int tx = threadIdx.x, ty = threadIdx.y;
#pragma unroll
  for (int i = 0; i < 4; ++i)
    tile[ty + 8 * i][tx] = src[(size_t)(r0 + ty + 8 * i) * C + c0 + tx];
  __syncthreads();
#pragma unroll
  for (int i = 0; i < 4; ++i)
    dst[(size_t)(c0 + ty + 8 * i) * R + r0 + tx] = f2bf(tile[tx][ty + 8 * i]);
}

// ---------------------------------------------------------------------------
// QKV projection: per (row-tile mt, head h, which in {q,k,v}):
//   out[s, n] = emb[s, :] @ W[h][:, n] + b[h][n]
// Q written pre-scaled by (1/sqrt(64)) * log2(e) so attention softmax runs
// natively in the exp2 domain. V written transposed [bh, dk, s].
// ---------------------------------------------------------------------------
__global__ __launch_bounds__(256) void qkv_kernel(
    const u16* __restrict__ emb, const u16* __restrict__ Wqt, const u16* __restrict__ Wkt,
    const u16* __restrict__ Wvt, const float* __restrict__ bq, const float* __restrict__ bk,
    const float* __restrict__ bv, u16* __restrict__ Q, u16* __restrict__ K,
    u16* __restrict__ Vt) {
  __shared__ alignas(16) u16 lds_a[64 * 64];
  __shared__ alignas(16) u16 lds_b[64 * 64];
  int tid = threadIdx.x, lane = tid & 63, wid = tid >> 6;
  int mt = blockIdx.x, h = blockIdx.y, which = blockIdx.z;
  const u16* Wt = (which == 0 ? Wqt : which == 1 ? Wkt : Wvt) + h * (ND * NK);
  const float* bias = (which == 0 ? bq : which == 1 ? bk : bv) + h * NK;
  int m0 = mt * 64;
  int col = lane & 15;
  f32x4 zero4 = {0.f, 0.f, 0.f, 0.f};
  f32x4 acc[4] = {zero4, zero4, zero4, zero4};
  for (int k0 = 0; k0 < ND; k0 += 64) {
    stage_tile(lds_a, emb + m0 * ND + k0, ND, wid, lane);
    stage_tile(lds_b, Wt + k0, ND, wid, lane);
    __syncthreads();
#pragma unroll
    for (int ks = 0; ks < 2; ++ks) {
      bf16x8 a = read_frag(lds_a, wid * 16 + col, ks, lane);
#pragma unroll
      for (int f = 0; f < 4; ++f) {
        bf16x8 b = read_frag(lds_b, f * 16 + col, ks, lane);
        acc[f] = __builtin_amdgcn_mfma_f32_16x16x32_bf16(a, b, acc[f], 0, 0, 0);
      }
    }
    __syncthreads();
  }
  int rbase = m0 + wid * 16 + (lane >> 4) * 4;
#pragma unroll
  for (int f = 0; f < 4; ++f) {
    int n = f * 16 + col;
    float bn = bias[n];
#pragma unroll
    for (int r = 0; r < 4; ++r) {
      int m = rbase + r;
      int b = m >> 11, s = m & (NS - 1);
      float v = acc[f][r] + bn;
      if (which == 0) {
        // fold 1/sqrt(dk) AND log2(e): softmax uses exp2 directly
        Q[((b * NH + h) * NS + s) * NK + n] = f2bf(v * 0.18033688f);
      } else if (which == 1) {
        K[((b * NH + h) * NS + s) * NK + n] = f2bf(v);
      } else {
        Vt[((b * NH + h) * NK + n) * NS + s] = f2bf(v);
      }
    }
  }
}

// ---------------------------------------------------------------------------
// Causal flash attention. 4 waves x 16 q-rows per 64-row q-tile. K-tiles of
// 64; causal => tiles t = 0..qt, only t==qt masks. Scores arrive in the exp2
// domain (log2e folded into Q).
//
// R3 changes (VALU-bound fix):
//  - pair q-tiles (qt, 31-qt) per block: every block = exactly 33 k-steps,
//    512 uniform blocks, no causal tail.
//  - defer-rescale (T13, THR=8 in log2 domain): skip alpha/acc/l rescale
//    unless a row max grew > 8.
//  - per-lane partial l accumulation; 16-lane reduce ONCE per q-tile.
//  - P -> bf16 via v_cvt_pk_bf16_f32 (8 ops vs ~64 integer RNE ops).
// ---------------------------------------------------------------------------
__global__ __launch_bounds__(256) void attn_kernel(const u16* __restrict__ Q,
                                                   const u16* __restrict__ K,
                                                   const u16* __restrict__ Vt,
                                                   u16* __restrict__ ctx) {
  __shared__ alignas(16) u16 lds_k[2][64 * 64];
  __shared__ alignas(16) u16 lds_v[2][64 * 64];
  __shared__ alignas(16) u16 p_lds[4][16 * 72];  // per-wave, stride 72 = conflict-free b128
  int tid = threadIdx.x, lane = tid & 63, wid = tid >> 6;
  int bh = blockIdx.x;
  int pr = blockIdx.y;  // pair index 0..15
  const u16* Qb = Q + bh * (NS * NK);
  const u16* Kb = K + bh * (NS * NK);
  const u16* Vb = Vt + bh * (NK * NS);
  int col = lane & 15;
  int b = bh >> 4, h = bh & 15;
  f32x4 zero4 = {0.f, 0.f, 0.f, 0.f};
  u16* pw = p_lds[wid];

#pragma unroll 1
  for (int half = 0; half < 2; ++half) {
    int qt = half ? pr : (31 - pr);  // (long, short) pair: 33 steps total
    int q0 = qt * 64;
    int qrow_a = q0 + wid * 16 + col;
    bf16x8 qf0 = *(const bf16x8*)(Qb + qrow_a * NK + (lane >> 4) * 8);
    bf16x8 qf1 = *(const bf16x8*)(Qb + qrow_a * NK + 32 + (lane >> 4) * 8);
    f32x4 acc[4] = {zero4, zero4, zero4, zero4};
    float m[4], lp[4];
#pragma unroll
    for (int r = 0; r < 4; ++r) { m[r] = -1e30f; lp[r] = 0.f; }
    int qrow_c = q0 + wid * 16 + (lane >> 4) * 4;
    int nt = qt + 1;

    // prologue: stage tile 0 into buffer 0
    stage_tile(lds_k[0], Kb, NK, wid, lane);
    stage_tile(lds_v[0], Vb, NS, wid, lane);
    __syncthreads();

    for (int t = 0; t < nt; ++t) {
      int cur = t & 1;
      if (t + 1 < nt) {  // prefetch next tile into the other buffer
        stage_tile(lds_k[cur ^ 1], Kb + (t + 1) * 64 * NK, NK, wid, lane);
        stage_tile(lds_v[cur ^ 1], Vb + (t + 1) * 64, NS, wid, lane);
      }
      const u16* lk = lds_k[cur];
      const u16* lv = lds_v[cur];
      // S = Q K^T (exp2 domain), C layout: col -> k-col, row -> q
      f32x4 sc[4];
#pragma unroll
      for (int f = 0; f < 4; ++f) {
        bf16x8 b0 = read_frag(lk, f * 16 + col, 0, lane);
        sc[f] = __builtin_amdgcn_mfma_f32_16x16x32_bf16(qf0, b0, zero4, 0, 0, 0);
        bf16x8 b1 = read_frag(lk, f * 16 + col, 1, lane);
        sc[f] = __builtin_amdgcn_mfma_f32_16x16x32_bf16(qf1, b1, sc[f], 0, 0, 0);
      }
      if (t == qt) {  // diagonal tile: causal mask k > q
#pragma unroll
        for (int f = 0; f < 4; ++f) {
          int kg = t * 64 + f * 16 + col;
#pragma unroll
          for (int r = 0; r < 4; ++r)
            if (kg > qrow_c + r) sc[f][r] = -1e30f;
        }
      }
      // row max: in-lane over 4 fragments, then 16-lane butterfly
      float mx[4];
#pragma unroll
      for (int r = 0; r < 4; ++r)
        mx[r] = fmaxf(fmaxf(sc[0][r], sc[1][r]), fmaxf(sc[2][r], sc[3][r]));
#pragma unroll
      for (int off = 1; off < 16; off <<= 1)
#pragma unroll
        for (int r = 0; r < 4; ++r) mx[r] = fmaxf(mx[r], __shfl_xor(mx[r], off));
      // defer-rescale: only rescale when some row grew past m + 8 (log2 dom.)
      bool ok = true;
#pragma unroll
      for (int r = 0; r < 4; ++r) ok = ok && (mx[r] <= m[r] + 8.0f);
      if (!__all(ok)) {
#pragma unroll
        for (int r = 0; r < 4; ++r) {
          float mn = fmaxf(m[r], mx[r]);
          float al = exp2f(m[r] - mn);
          m[r] = mn;
          lp[r] *= al;
#pragma unroll
          for (int f = 0; f < 4; ++f) acc[f][r] *= al;
        }
      }
      // P = exp2(S - m); accumulate per-lane partial row sums (reduced once
      // per q-tile at the end)
#pragma unroll
      for (int f = 0; f < 4; ++f)
#pragma unroll
        for (int r = 0; r < 4; ++r) {
          float p = exp2f(sc[f][r] - m[r]);
          sc[f][r] = p;
          lp[r] += p;
        }
      // P (C layout) -> per-wave LDS slab, packed bf16 converts
#pragma unroll
      for (int f = 0; f < 4; ++f)
#pragma unroll
        for (int rp = 0; rp < 4; rp += 2) {
          u32 u = cvt_pk_bf16(sc[f][rp], sc[f][rp + 1]);
          int row = (lane >> 4) * 4 + rp;
          pw[row * 72 + f * 16 + col] = (u16)u;
          pw[(row + 1) * 72 + f * 16 + col] = (u16)(u >> 16);
        }
#pragma unroll
      for (int ks = 0; ks < 2; ++ks) {
        bf16x8 pa = *(const bf16x8*)(pw + col * 72 + ks * 32 + (lane >> 4) * 8);
#pragma unroll
        for (int f = 0; f < 4; ++f) {
          bf16x8 vb = read_frag(lv, f * 16 + col, ks, lane);
          acc[f] = __builtin_amdgcn_mfma_f32_16x16x32_bf16(pa, vb, acc[f], 0, 0, 0);
        }
      }
      // single barrier per step: LDS reads of buf[cur] done + prefetch landed
      __syncthreads();
    }
    // reduce per-lane partial l across the 16-lane row group (once per tile)
#pragma unroll
    for (int off = 1; off < 16; off <<= 1)
#pragma unroll
      for (int r = 0; r < 4; ++r) lp[r] += __shfl_xor(lp[r], off);
    // normalize + write ctx as [b][s][h*64+dk] (head-major concat)
#pragma unroll
    for (int r = 0; r < 4; ++r) {
      float inv = 1.0f / lp[r];
      int s = qrow_c + r;
#pragma unroll
      for (int f = 0; f < 4; ++f)
        ctx[(b * NS + s) * ND + h * NK + f * 16 + col] = f2bf(acc[f][r] * inv);
    }
  }
}

// ---------------------------------------------------------------------------
// Output projection: out[m, n] = ctx[m, :] @ Wo[:, n] + bo[n], f32 out.
// ---------------------------------------------------------------------------
__global__ __launch_bounds__(256) void outproj_kernel(const u16* __restrict__ ctx,
                                                      const u16* __restrict__ Wot,
                                                      const float* __restrict__ bo,
                                                      float* __restrict__ out) {
  __shared__ alignas(16) u16 lds_a[64 * 64];
  __shared__ alignas(16) u16 lds_b[64 * 64];
  int tid = threadIdx.x, lane = tid & 63, wid = tid >> 6;
  int m0 = blockIdx.x * 64, n0 = blockIdx.y * 64;
  int col = lane & 15;
  f32x4 zero4 = {0.f, 0.f, 0.f, 0.f};
  f32x4 acc[4] = {zero4, zero4, zero4, zero4};
  for (int k0 = 0; k0 < ND; k0 += 64) {
    stage_tile(lds_a, ctx + m0 * ND + k0, ND, wid, lane);
    stage_tile(lds_b, Wot + n0 * ND + k0, ND, wid, lane);
    __syncthreads();
#pragma unroll
    for (int ks = 0; ks < 2; ++ks) {
      bf16x8 a = read_frag(lds_a, wid * 16 + col, ks, lane);
#pragma unroll
      for (int f = 0; f < 4; ++f) {
        bf16x8 b = read_frag(lds_b, f * 16 + col, ks, lane);
        acc[f] = __builtin_amdgcn_mfma_f32_16x16x32_bf16(a, b, acc[f], 0, 0, 0);
      }
    }
    __syncthreads();
  }
  int rbase = m0 + wid * 16 + (lane >> 4) * 4;
#pragma unroll
  for (int f = 0; f < 4; ++f) {
    int n = n0 + f * 16 + col;
    float bn = bo[n];
#pragma unroll
    for (int r = 0; r < 4; ++r) out[(rbase + r) * ND + n] = acc[f][r] + bn;
  }
}

// ---------------------------------------------------------------------------
extern "C" void kernel_launch(void* const* d_in, const int* in_sizes, int n_in,
                              void* d_out, int out_size, void* d_ws, size_t ws_size,
                              hipStream_t stream) {
  (void)in_sizes; (void)n_in; (void)out_size;
  const float* emb = (const float*)d_in[0];
  const float* Wq = (const float*)d_in[1];
  const float* bq = (const float*)d_in[2];
  const float* Wk = (const float*)d_in[3];
  const float* bk = (const float*)d_in[4];
  const float* Wv = (const float*)d_in[5];
  const float* bv = (const float*)d_in[6];
  const float* Wo = (const float*)d_in[7];
  const float* bo = (const float*)d_in[8];
  float* out = (float*)d_out;

  const size_t EMB_N = (size_t)NB * NS * ND;      // 4194304
  const size_t W_N = (size_t)NH * ND * NK;        // 1048576
  const size_t QKV_N = (size_t)NB * NH * NS * NK; // 4194304
  // ws layout (u16 elems). ctx aliases emb_bf (emb consumed before ctx written).
  if (ws_size < (EMB_N + 4 * W_N + 3 * QKV_N) * sizeof(u16)) return;
  u16* ws = (u16*)d_ws;
  u16* emb_bf = ws;
  u16* Wqt = emb_bf + EMB_N;
  u16* Wkt = Wqt + W_N;
  u16* Wvt = Wkt + W_N;
  u16* Wot = Wvt + W_N;
  u16* Qb = Wot + W_N;
  u16* Kb = Qb + QKV_N;
  u16* Vtb = Kb + QKV_N;
  u16* ctxb = emb_bf;  // alias

  convert_kernel<<<dim3((int)(EMB_N / 4 / 256)), dim3(256), 0, stream>>>(emb, emb_bf,
                                                                         (int)EMB_N);
  dim3 tb(32, 8);
  transpose_conv<<<dim3(2, 32, 16), tb, 0, stream>>>(Wq, Wqt, ND, NK);
  transpose_conv<<<dim3(2, 32, 16), tb, 0, stream>>>(Wk, Wkt, ND, NK);
  transpose_conv<<<dim3(2, 32, 16), tb, 0, stream>>>(Wv, Wvt, ND, NK);
  transpose_conv<<<dim3(32, 32, 1), tb, 0, stream>>>(Wo, Wot, ND, ND);
  qkv_kernel<<<dim3(64, 16, 3), dim3(256), 0, stream>>>(emb_bf, Wqt, Wkt, Wvt, bq, bk, bv,
                                                        Qb, Kb, Vtb);
  attn_kernel<<<dim3(32, 16), dim3(256), 0, stream>>>(Qb, Kb, Vtb, ctxb);
  outproj_kernel<<<dim3(64, 16), dim3(256), 0, stream>>>(ctxb, Wot, bo, out);
}

// Round 5
// 138.393 us; speedup vs baseline: 1.5663x; 1.0089x over previous
//
#include <hip/hip_runtime.h>
#include <hip/hip_bf16.h>

typedef unsigned short u16;
typedef unsigned int u32;
typedef __bf16 bf16x8 __attribute__((ext_vector_type(8)));
typedef float f32x4 __attribute__((ext_vector_type(4)));
typedef float f32x16 __attribute__((ext_vector_type(16)));

#define AS1 __attribute__((address_space(1)))
#define AS3 __attribute__((address_space(3)))

#define NB 2
#define NS 2048
#define ND 1024
#define NH 16
#define NK 64

__device__ __forceinline__ u16 f2bf(float f) {
  u32 u = __builtin_bit_cast(u32, f);
  return (u16)((u + 0x7FFFu + ((u >> 16) & 1u)) >> 16);  // RNE
}

// packed f32x2 -> bf16x2 (RNE) in one VALU op; no builtin on gfx950 (m240)
__device__ __forceinline__ u32 cvt_pk_bf16(float lo, float hi) {
  u32 u;
  asm("v_cvt_pk_bf16_f32 %0, %1, %2" : "=v"(u) : "v"(lo), "v"(hi));
  return u;
}

// ---------------------------------------------------------------------------
// Stage a 64x64 bf16 tile (global row stride rs elems) into LDS.
// LDS is linear [64][64]; logical 16B-slot s of row r lives at physical slot
// s ^ (r&7). global_load_lds writes linearly, so the swizzle is applied by
// permuting the per-lane GLOBAL source address (both-sides-or-neither rule).
// ---------------------------------------------------------------------------
__device__ __forceinline__ void stage_tile(u16* lds, const u16* __restrict__ src, int rs,
                                           int wid, int lane) {
#pragma unroll
  for (int i = 0; i < 2; ++i) {
    int c = wid * 128 + i * 64 + lane;  // 16B chunk id, 0..511
    int row = c >> 3;
    int kc = (c & 7) ^ (row & 7);       // pre-swizzled source slot
    __builtin_amdgcn_global_load_lds((const AS1 u32*)(src + row * rs + kc * 8),
                                     (AS3 u32*)(lds + (wid * 128 + i * 64) * 8), 16, 0, 0);
  }
}

// Read the 8-elem (16B) fragment at LDS row `row`, 16B-slot `slot` (swizzled).
__device__ __forceinline__ bf16x8 read_slot(const u16* lds, int row, int slot) {
  return *(const bf16x8*)(lds + row * 64 + (slot ^ (row & 7)) * 8);
}

// Read 4 bf16 (8B) at (row, col..col+3), col % 4 == 0, through the swizzle.
__device__ __forceinline__ uint2 ld8(const u16* lds, int row, int col) {
  int slot = (col >> 3) ^ (row & 7);
  return *(const uint2*)(lds + row * 64 + slot * 8 + (col & 7));
}

// V B-fragment with k enumerated in C-layout (crow) order: element j holds
// V[k = ks*16 + (j&3) + 8*(j>>2) + 4*hi][row]. Pairing-invariant with P fed
// in natural C-layout register order (no cross-lane reshuffle needed).
__device__ __forceinline__ bf16x8 read_vfrag(const u16* lds, int row, int ks, int hi) {
  int c0 = ks * 16 + 4 * hi;
  uint2 a = ld8(lds, row, c0);
  uint2 b = ld8(lds, row, c0 + 8);
  uint4 q; q.x = a.x; q.y = a.y; q.z = b.x; q.w = b.y;
  return __builtin_bit_cast(bf16x8, q);
}

// Read the MFMA operand fragment at logical (row, k = ks*32 + (lane>>4)*8).
__device__ __forceinline__ bf16x8 read_frag(const u16* lds, int row, int ks, int lane) {
  int slot = ((lane >> 4) + ks * 4) ^ (row & 7);
  return *(const bf16x8*)(lds + row * 64 + slot * 8);
}

// ---------------------------------------------------------------------------
// f32 -> bf16 convert (emb)
// ---------------------------------------------------------------------------
__global__ __launch_bounds__(256) void convert_kernel(const float* __restrict__ src,
                                                      u16* __restrict__ dst, int n) {
  int i = (blockIdx.x * 256 + threadIdx.x) * 4;
  if (i >= n) return;
  float4 v = *(const float4*)(src + i);
  u32 w0 = cvt_pk_bf16(v.x, v.y);
  u32 w1 = cvt_pk_bf16(v.z, v.w);
  uint2 w; w.x = w0; w.y = w1;
  *(uint2*)(dst + i) = w;
}

// ---------------------------------------------------------------------------
// Transposing f32->bf16 convert: src [R][C] f32 (per z), dst [C][R] bf16.
// ---------------------------------------------------------------------------
__global__ __launch_bounds__(256) void transpose_conv(const float* __restrict__ src,
                                                      u16* __restrict__ dst, int R, int C) {
  __shared__ float tile[32][33];
  size_t base = (size_t)blockIdx.z * R * C;
  src += base;
  dst += base;
  int c0 = blockIdx.x * 32, r0 = blockIdx.y * 32;
  int tx = threadIdx.x, ty = threadIdx.y;
#pragma unroll
  for (int i = 0; i < 4; ++i)
    tile[ty + 8 * i][tx] = src[(size_t)(r0 + ty + 8 * i) * C + c0 + tx];
  __syncthreads();
#pragma unroll
  for (int i = 0; i < 4; ++i)
    dst[(size_t)(c0 + ty + 8 * i) * R + r0 + tx] = f2bf(tile[tx][ty + 8 * i]);
}

// ---------------------------------------------------------------------------
// QKV projection (unchanged, passing since R1).
// ---------------------------------------------------------------------------
__global__ __launch_bounds__(256) void qkv_kernel(
    const u16* __restrict__ emb, const u16* __restrict__ Wqt, const u16* __restrict__ Wkt,
    const u16* __restrict__ Wvt, const float* __restrict__ bq, const float* __restrict__ bk,
    const float* __restrict__ bv, u16* __restrict__ Q, u16* __restrict__ K,
    u16* __restrict__ Vt) {
  __shared__ alignas(16) u16 lds_a[64 * 64];
  __shared__ alignas(16) u16 lds_b[64 * 64];
  int tid = threadIdx.x, lane = tid & 63, wid = tid >> 6;
  int mt = blockIdx.x, h = blockIdx.y, which = blockIdx.z;
  const u16* Wt = (which == 0 ? Wqt : which == 1 ? Wkt : Wvt) + h * (ND * NK);
  const float* bias = (which == 0 ? bq : which == 1 ? bk : bv) + h * NK;
  int m0 = mt * 64;
  int col = lane & 15;
  f32x4 zero4 = {0.f, 0.f, 0.f, 0.f};
  f32x4 acc[4] = {zero4, zero4, zero4, zero4};
  for (int k0 = 0; k0 < ND; k0 += 64) {
    stage_tile(lds_a, emb + m0 * ND + k0, ND, wid, lane);
    stage_tile(lds_b, Wt + k0, ND, wid, lane);
    __syncthreads();
#pragma unroll
    for (int ks = 0; ks < 2; ++ks) {
      bf16x8 a = read_frag(lds_a, wid * 16 + col, ks, lane);
#pragma unroll
      for (int f = 0; f < 4; ++f) {
        bf16x8 b = read_frag(lds_b, f * 16 + col, ks, lane);
        acc[f] = __builtin_amdgcn_mfma_f32_16x16x32_bf16(a, b, acc[f], 0, 0, 0);
      }
    }
    __syncthreads();
  }
  int rbase = m0 + wid * 16 + (lane >> 4) * 4;
#pragma unroll
  for (int f = 0; f < 4; ++f) {
    int n = f * 16 + col;
    float bn = bias[n];
#pragma unroll
    for (int r = 0; r < 4; ++r) {
      int m = rbase + r;
      int b = m >> 11, s = m & (NS - 1);
      float v = acc[f][r] + bn;
      if (which == 0) {
        // fold 1/sqrt(dk) AND log2(e): softmax uses exp2 directly
        Q[((b * NH + h) * NS + s) * NK + n] = f2bf(v * 0.18033688f);
      } else if (which == 1) {
        K[((b * NH + h) * NS + s) * NK + n] = f2bf(v);
      } else {
        Vt[((b * NH + h) * NK + n) * NS + s] = f2bf(v);
      }
    }
  }
}

// ---------------------------------------------------------------------------
// Causal flash attention, R5: 32x32 MFMA + swapped QK^T, de-risked.
//
//  vs R4 (failed): removed BOTH unverified primitives.
//   - cross-half (lane^32) exchange of running max / row-sum: __shfl_xor(,32)
//     (standard HIP) instead of v_permlane32_swap_b32.
//   - P -> PV A-frags: fed in NATURAL C-layout register order (no reshuffle);
//     the V B-fragment is read with the SAME crow k-enumeration (two 8B LDS
//     reads per fragment). MFMA pairs element j with element j, so the PV sum
//     is invariant to the (unknown) position->k bijection — layout risk gone.
//  Everything else identical to R4: 4 warps x 32 q-rows, KVBLK=64 dbuf,
//  prefetch-top + 1 barrier, defer-rescale THR=8 (exp2 domain), slab
//  redistribution of per-q scalars, paired-qt dispatch for load balance.
// ---------------------------------------------------------------------------
__global__ __launch_bounds__(256, 2) void attn_kernel(const u16* __restrict__ Q,
                                                      const u16* __restrict__ K,
                                                      const u16* __restrict__ Vt,
                                                      u16* __restrict__ ctx) {
  __shared__ alignas(16) u16 lds_k[2][64 * 64];
  __shared__ alignas(16) u16 lds_v[2][64 * 64];
  __shared__ float slab[4][32];
  int tid = threadIdx.x, lane = tid & 63, w = tid >> 6;
  int hi = lane >> 5, ln = lane & 31;
  int bh = blockIdx.x;
  int y = blockIdx.y;
  int qt = (y < 8) ? (15 - y) : (y - 8);
  const u16* Qb = Q + bh * (NS * NK);
  const u16* Kb = K + bh * (NS * NK);
  const u16* Vb = Vt + bh * (NK * NS);
  int q0w = qt * 128 + w * 32;
  int qg = q0w + ln;  // this lane's q row (global s index)
  // Q B-frags: B[col=q=ln][kk=ks*16+hi*8+j], held in regs all block
  bf16x8 qf[4];
#pragma unroll
  for (int ks = 0; ks < 4; ++ks)
    qf[ks] = *(const bf16x8*)(Qb + qg * NK + ks * 16 + hi * 8);

  f32x16 acc0, acc1;
#pragma unroll
  for (int r = 0; r < 16; ++r) { acc0[r] = 0.f; acc1[r] = 0.f; }
  float m = -1e30f, lp = 0.f;
  int nt = 2 * qt + 2;
  int tmaxw = (q0w + 31) >> 6;  // last (masked) k-tile this warp computes

  stage_tile(lds_k[0], Kb, NK, w, lane);
  stage_tile(lds_v[0], Vb, NS, w, lane);
  __syncthreads();

  for (int t = 0; t < nt; ++t) {
    int cur = t & 1;
    if (t + 1 < nt) {  // prefetch next tile into the other buffer
      stage_tile(lds_k[cur ^ 1], Kb + (t + 1) * 64 * NK, NK, w, lane);
      stage_tile(lds_v[cur ^ 1], Vb + (t + 1) * 64, NS, w, lane);
    }
    if (t <= tmaxw) {
      const u16* lk = lds_k[cur];
      const u16* lv = lds_v[cur];
      // ---- S^T = K · Q^T  (two 32-k blocks) ----
      f32x16 sc0, sc1;
#pragma unroll
      for (int r = 0; r < 16; ++r) { sc0[r] = 0.f; sc1[r] = 0.f; }
      __builtin_amdgcn_s_setprio(1);
#pragma unroll
      for (int ks = 0; ks < 4; ++ks) {
        bf16x8 kf0 = read_slot(lk, ln, 2 * ks + hi);
        sc0 = __builtin_amdgcn_mfma_f32_32x32x16_bf16(kf0, qf[ks], sc0, 0, 0, 0);
        bf16x8 kf1 = read_slot(lk, 32 + ln, 2 * ks + hi);
        sc1 = __builtin_amdgcn_mfma_f32_32x32x16_bf16(kf1, qf[ks], sc1, 0, 0, 0);
      }
      __builtin_amdgcn_s_setprio(0);
      // sc0[r] = S[k = t*64 + crow(r,hi)][q=qg], sc1: k += 32,
      // crow(r,hi) = (r&3) + 8*(r>>2) + 4*hi   (C-layout, HW-verified)
      if (t == tmaxw) {  // causal mask: k_global > q
#pragma unroll
        for (int r = 0; r < 16; ++r) {
          int kl = t * 64 + (r & 3) + 8 * (r >> 2) + 4 * hi;
          if (kl > qg) sc0[r] = -1e30f;
          if (kl + 32 > qg) sc1[r] = -1e30f;
        }
      }
      // ---- row max: in-register fmax tree + cross-half shfl ----
      float mt_[16];
#pragma unroll
      for (int i = 0; i < 16; ++i) mt_[i] = fmaxf(sc0[i], sc1[i]);
#pragma unroll
      for (int s = 8; s > 0; s >>= 1)
#pragma unroll
        for (int i = 0; i < s; ++i) mt_[i] = fmaxf(mt_[i], mt_[i + s]);
      float mx = mt_[0];
      mx = fmaxf(mx, __shfl_xor(mx, 32));
      // ---- defer-rescale (THR=8 in exp2 domain) ----
      if (__any(mx > m + 8.0f)) {
        float mn = fmaxf(m, mx);
        float al = exp2f(m - mn);
        m = mn;
        lp *= al;
        if (!hi) slab[w][ln] = al;
        float av[16];
#pragma unroll
        for (int r = 0; r < 16; ++r) av[r] = slab[w][(r & 3) + 8 * (r >> 2) + 4 * hi];
#pragma unroll
        for (int r = 0; r < 16; ++r) { acc0[r] *= av[r]; acc1[r] *= av[r]; }
      }
      // ---- P = exp2(S - m), per-lane partial row sum ----
      float ps[4] = {0.f, 0.f, 0.f, 0.f};
#pragma unroll
      for (int r = 0; r < 16; ++r) {
        float p = exp2f(sc0[r] - m);
        sc0[r] = p;
        ps[r & 3] += p;
      }
#pragma unroll
      for (int r = 0; r < 16; ++r) {
        float p = exp2f(sc1[r] - m);
        sc1[r] = p;
        ps[r & 3] += p;
      }
      lp += (ps[0] + ps[1]) + (ps[2] + ps[3]);
      // ---- P -> PV A-frags in natural C-layout order (no reshuffle) ----
      u32 wd[8];
      bf16x8 pa[4];
#pragma unroll
      for (int i = 0; i < 8; ++i) wd[i] = cvt_pk_bf16(sc0[2 * i], sc0[2 * i + 1]);
      { uint4 q4; q4.x = wd[0]; q4.y = wd[1]; q4.z = wd[2]; q4.w = wd[3];
        pa[0] = __builtin_bit_cast(bf16x8, q4);
        q4.x = wd[4]; q4.y = wd[5]; q4.z = wd[6]; q4.w = wd[7];
        pa[1] = __builtin_bit_cast(bf16x8, q4); }
#pragma unroll
      for (int i = 0; i < 8; ++i) wd[i] = cvt_pk_bf16(sc1[2 * i], sc1[2 * i + 1]);
      { uint4 q4; q4.x = wd[0]; q4.y = wd[1]; q4.z = wd[2]; q4.w = wd[3];
        pa[2] = __builtin_bit_cast(bf16x8, q4);
        q4.x = wd[4]; q4.y = wd[5]; q4.z = wd[6]; q4.w = wd[7];
        pa[3] = __builtin_bit_cast(bf16x8, q4); }
      // ---- PV: acc[vb] += sum_ks pa[ks] * Vfrag[vb][ks] (crow-enumerated) --
      __builtin_amdgcn_s_setprio(1);
#pragma unroll
      for (int ks = 0; ks < 4; ++ks) {
        bf16x8 vf0 = read_vfrag(lv, ln, ks, hi);
        acc0 = __builtin_amdgcn_mfma_f32_32x32x16_bf16(pa[ks], vf0, acc0, 0, 0, 0);
        bf16x8 vf1 = read_vfrag(lv, 32 + ln, ks, hi);
        acc1 = __builtin_amdgcn_mfma_f32_32x32x16_bf16(pa[ks], vf1, acc1, 0, 0, 0);
      }
      __builtin_amdgcn_s_setprio(0);
    }
    __syncthreads();  // buf[cur] reads done + prefetch drained (vmcnt 0)
  }
  // ---- epilogue: merge lp halves, redistribute 1/l, write ctx ----
  lp += __shfl_xor(lp, 32);
  if (!hi) slab[w][ln] = 1.0f / lp;
  float iv[16];
#pragma unroll
  for (int r = 0; r < 16; ++r) iv[r] = slab[w][(r & 3) + 8 * (r >> 2) + 4 * hi];
  int b = bh >> 4, h = bh & 15;
#pragma unroll
  for (int r = 0; r < 16; ++r) {
    int qq = q0w + (r & 3) + 8 * (r >> 2) + 4 * hi;
    size_t base = (size_t)(b * NS + qq) * ND + h * NK + ln;
    ctx[base] = f2bf(acc0[r] * iv[r]);
    ctx[base + 32] = f2bf(acc1[r] * iv[r]);
  }
}

// ---------------------------------------------------------------------------
// Output projection: out[m, n] = ctx[m, :] @ Wo[:, n] + bo[n], f32 out.
// ---------------------------------------------------------------------------
__global__ __launch_bounds__(256) void outproj_kernel(const u16* __restrict__ ctx,
                                                      const u16* __restrict__ Wot,
                                                      const float* __restrict__ bo,
                                                      float* __restrict__ out) {
  __shared__ alignas(16) u16 lds_a[64 * 64];
  __shared__ alignas(16) u16 lds_b[64 * 64];
  int tid = threadIdx.x, lane = tid & 63, wid = tid >> 6;
  int m0 = blockIdx.x * 64, n0 = blockIdx.y * 64;
  int col = lane & 15;
  f32x4 zero4 = {0.f, 0.f, 0.f, 0.f};
  f32x4 acc[4] = {zero4, zero4, zero4, zero4};
  for (int k0 = 0; k0 < ND; k0 += 64) {
    stage_tile(lds_a, ctx + m0 * ND + k0, ND, wid, lane);
    stage_tile(lds_b, Wot + n0 * ND + k0, ND, wid, lane);
    __syncthreads();
#pragma unroll
    for (int ks = 0; ks < 2; ++ks) {
      bf16x8 a = read_frag(lds_a, wid * 16 + col, ks, lane);
#pragma unroll
      for (int f = 0; f < 4; ++f) {
        bf16x8 b = read_frag(lds_b, f * 16 + col, ks, lane);
        acc[f] = __builtin_amdgcn_mfma_f32_16x16x32_bf16(a, b, acc[f], 0, 0, 0);
      }
    }
    __syncthreads();
  }
  int rbase = m0 + wid * 16 + (lane >> 4) * 4;
#pragma unroll
  for (int f = 0; f < 4; ++f) {
    int n = n0 + f * 16 + col;
    float bn = bo[n];
#pragma unroll
    for (int r = 0; r < 4; ++r) out[(rbase + r) * ND + n] = acc[f][r] + bn;
  }
}

// ---------------------------------------------------------------------------
extern "C" void kernel_launch(void* const* d_in, const int* in_sizes, int n_in,
                              void* d_out, int out_size, void* d_ws, size_t ws_size,
                              hipStream_t stream) {
  (void)in_sizes; (void)n_in; (void)out_size;
  const float* emb = (const float*)d_in[0];
  const float* Wq = (const float*)d_in[1];
  const float* bq = (const float*)d_in[2];
  const float* Wk = (const float*)d_in[3];
  const float* bk = (const float*)d_in[4];
  const float* Wv = (const float*)d_in[5];
  const float* bv = (const float*)d_in[6];
  const float* Wo = (const float*)d_in[7];
  const float* bo = (const float*)d_in[8];
  float* out = (float*)d_out;

  const size_t EMB_N = (size_t)NB * NS * ND;      // 4194304
  const size_t W_N = (size_t)NH * ND * NK;        // 1048576
  const size_t QKV_N = (size_t)NB * NH * NS * NK; // 4194304
  if (ws_size < (EMB_N + 4 * W_N + 3 * QKV_N) * sizeof(u16)) return;
  u16* ws = (u16*)d_ws;
  u16* emb_bf = ws;
  u16* Wqt = emb_bf + EMB_N;
  u16* Wkt = Wqt + W_N;
  u16* Wvt = Wkt + W_N;
  u16* Wot = Wvt + W_N;
  u16* Qb = Wot + W_N;
  u16* Kb = Qb + QKV_N;
  u16* Vtb = Kb + QKV_N;
  u16* ctxb = emb_bf;  // alias (emb consumed before ctx written)

  convert_kernel<<<dim3((int)(EMB_N / 4 / 256)), dim3(256), 0, stream>>>(emb, emb_bf,
                                                                         (int)EMB_N);
  dim3 tb(32, 8);
  transpose_conv<<<dim3(2, 32, 16), tb, 0, stream>>>(Wq, Wqt, ND, NK);
  transpose_conv<<<dim3(2, 32, 16), tb, 0, stream>>>(Wk, Wkt, ND, NK);
  transpose_conv<<<dim3(2, 32, 16), tb, 0, stream>>>(Wv, Wvt, ND, NK);
  transpose_conv<<<dim3(32, 32, 1), tb, 0, stream>>>(Wo, Wot, ND, ND);
  qkv_kernel<<<dim3(64, 16, 3), dim3(256), 0, stream>>>(emb_bf, Wqt, Wkt, Wvt, bq, bk, bv,
                                                        Qb, Kb, Vtb);
  attn_kernel<<<dim3(32, 16), dim3(256), 0, stream>>>(Qb, Kb, Vtb, ctxb);
  outproj_kernel<<<dim3(64, 16), dim3(256), 0, stream>>>(ctxb, Wot, bo, out);
}